// Round 13
// baseline (408.709 us; speedup 1.0000x reference)
//
#include <hip/hip_runtime.h>
#include <hip/hip_bf16.h>
#include <math.h>

#define B_SZ 2
#define SEQLEN 2048
#define D_MODEL 1024
#define D_INNER 2048
#define D_STATE 16
#define D_CONV 4
#define DT_RANK 64
#define NTOK (B_SZ * SEQLEN)      /* 4096 */
#define XDBL 96                   /* DT_RANK + 2*D_STATE */
#define NC 32                     /* scan chunks */
#define LC 64                     /* chunk length */
#define PADTOT (17 * 256)         /* padded perm length (256-aligned experts) */

typedef float f32x4 __attribute__((ext_vector_type(4)));
typedef unsigned int u32x4 __attribute__((ext_vector_type(4)));
typedef __hip_bfloat16 bf16;

__device__ __forceinline__ float siluf(float v) { return v / (1.f + __expf(-v)); }
__device__ __forceinline__ float softplusf(float v) { return (v > 20.f) ? v : log1pf(__expf(v)); }

__device__ __forceinline__ void mfma_bf16(f32x4& acc, u32x4 a, u32x4 b) {
  asm volatile("v_mfma_f32_16x16x32_bf16 %0, %1, %2, %0" : "+v"(acc) : "v"(a), "v"(b));
}

__device__ __forceinline__ void gload16(const bf16* g, bf16* l) {
  __builtin_amdgcn_global_load_lds(
      (const __attribute__((address_space(1))) unsigned int*)g,
      (__attribute__((address_space(3))) unsigned int*)l, 16, 0, 0);
}

// ---- token partition by expert, padded so every 256-row panel is pure-expert.
__global__ __launch_bounds__(1024) void k_perm(const int* __restrict__ ids, int* __restrict__ perm) {
  __shared__ int sc[1024];
  const int tid = threadIdx.x;
  int loc[4];
  int cnt = 0;
#pragma unroll
  for (int q = 0; q < 4; q++) {
    loc[q] = ids[tid * 4 + q];
    cnt += (loc[q] == 0);
  }
  sc[tid] = cnt;
  __syncthreads();
  for (int off = 1; off < 1024; off <<= 1) {
    int v = sc[tid];
    int u = (tid >= off) ? sc[tid - off] : 0;
    __syncthreads();
    sc[tid] = v + u;
    __syncthreads();
  }
  const int N0 = sc[1023];
  const int m0 = (N0 + 255) & ~255;
  const int N1 = NTOK - N0;
  for (int idx = tid; idx < PADTOT; idx += 1024)
    if ((idx >= N0 && idx < m0) || idx >= m0 + N1) perm[idx] = -1;
  int zb = sc[tid] - cnt;
#pragma unroll
  for (int q = 0; q < 4; q++) {
    int t = tid * 4 + q;
    if (loc[q] == 0) { perm[zb] = t; zb++; }
    else             { perm[m0 + (t - zb)] = t; }
  }
}

// ---- fused fp32 -> bf16 conversion of h and all GEMM weights
#define CVT_H   (NTOK * D_MODEL)
#define CVT_WIN (2 * 2 * D_INNER * D_MODEL)
#define CVT_WX  (2 * XDBL * D_INNER)
#define CVT_WDT (2 * D_INNER * DT_RANK)
#define CVT_WO  (2 * D_MODEL * D_INNER)
#define CVT_TOT (CVT_H + CVT_WIN + CVT_WX + CVT_WDT + CVT_WO)
__global__ __launch_bounds__(256) void k_cvtall(const float* __restrict__ h,
                                                const float* __restrict__ Win,
                                                const float* __restrict__ Wx,
                                                const float* __restrict__ Wdt,
                                                const float* __restrict__ Wout,
                                                bf16* __restrict__ hB, bf16* __restrict__ WinB,
                                                bf16* __restrict__ WxB, bf16* __restrict__ WdtB,
                                                bf16* __restrict__ WoB) {
  size_t i = ((size_t)blockIdx.x * 256 + threadIdx.x) * 8;
  const float* src; bf16* dst; size_t off;
  if (i < CVT_H)                          { src = h;    dst = hB;   off = i; }
  else if (i < CVT_H + CVT_WIN)           { src = Win;  dst = WinB; off = i - CVT_H; }
  else if (i < CVT_H + CVT_WIN + CVT_WX)  { src = Wx;   dst = WxB;  off = i - CVT_H - CVT_WIN; }
  else if (i < CVT_TOT - CVT_WO)          { src = Wdt;  dst = WdtB; off = i - CVT_H - CVT_WIN - CVT_WX; }
  else                                    { src = Wout; dst = WoB;  off = i - (CVT_TOT - CVT_WO); }
  float4 f0 = *(const float4*)&src[off];
  float4 f1 = *(const float4*)&src[off + 4];
  __align__(16) bf16 tmp[8];
  tmp[0] = __float2bfloat16(f0.x); tmp[1] = __float2bfloat16(f0.y);
  tmp[2] = __float2bfloat16(f0.z); tmp[3] = __float2bfloat16(f0.w);
  tmp[4] = __float2bfloat16(f1.x); tmp[5] = __float2bfloat16(f1.y);
  tmp[6] = __float2bfloat16(f1.z); tmp[7] = __float2bfloat16(f1.w);
  *(u32x4*)&dst[off] = *(const u32x4*)tmp;
}

// ---- deep-pipelined 256x128 GEMM body (ring-3 LDS, depth-2 prefetch, counted vmcnt).
// EPI 0 (in-proj): col<2048 -> outx bf16; else -> outz bf16.
// EPI 1 (out-proj): fp32 partial out0[(kz*NTOK+t)*D_MODEL + col].
template <int KDIM, int NW, int KSPLIT, int EPI>
__device__ __forceinline__ void gemmP_body(const bf16* __restrict__ actB,
                                           const int* __restrict__ perm,
                                           const int* __restrict__ ids,
                                           const bf16* __restrict__ WB,
                                           bf16* __restrict__ outx,
                                           bf16* __restrict__ outz,
                                           float* __restrict__ out0) {
  constexpr int KLEN = KDIM / KSPLIT;
  constexpr int NT = KLEN / 64;      // 16 for both instances
  constexpr int NCOL = (EPI == 1) ? (D_MODEL / 128) : 0;
  __shared__ bf16 As[3][256 * 64];   // 96 KB
  __shared__ bf16 Ws[3][128 * 64];   // 48 KB
  const int tid = threadIdx.x;

  const int gx = gridDim.x;
  const int nwg = gx * gridDim.y;
  const int fid = blockIdx.y * gx + blockIdx.x;
  const int q8 = nwg >> 3;
  const int swz = (fid & 7) * q8 + (fid >> 3);
  const int bx = swz % gx, by = swz / gx;
  const int ot = (KSPLIT > 1) ? (bx % NCOL) * 128 : bx * 128;
  const int kz = (KSPLIT > 1) ? bx / NCOL : 0;
  const int kbase = kz * KLEN;
  const int tt = by * 256;

  const int lane = tid & 63, w = tid >> 6;  // 8 waves
  const int wr = w >> 1, wc = w & 1;        // 4M x 2N
  const int lr = lane & 15, lg = lane >> 4;

  const int t00 = perm[tt];
  const int eu = (t00 >= 0) ? ids[t00] : 0;
  const size_t wexp = (size_t)eu * NW * KDIM;

  const int kswz = ((lane & 7) ^ ((lane >> 3) & 7)) * 8;
  size_t aBase[4]; int aLds[4];
  size_t bBase[2]; int bLds[2];
#pragma unroll
  for (int v = 0; v < 4; v++) {
    const int row = w * 32 + v * 8 + (lane >> 3);
    int ta = perm[tt + row]; if (ta < 0) ta = 0;
    aBase[v] = (size_t)ta * KDIM + kswz;
    aLds[v] = (w * 32 + v * 8) * 64;
  }
#pragma unroll
  for (int v = 0; v < 2; v++) {
    const int row = w * 16 + v * 8 + (lane >> 3);
    bBase[v] = wexp + (size_t)(ot + row) * KDIM + kswz;
    bLds[v] = (w * 16 + v * 8) * 64;
  }

  f32x4 acc[4][4];
#pragma unroll
  for (int i = 0; i < 4; i++)
#pragma unroll
    for (int j = 0; j < 4; j++) acc[i][j] = (f32x4){0.f, 0.f, 0.f, 0.f};

#pragma unroll
  for (int kt = 0; kt < 2; kt++) {
    const int k0 = kbase + kt * 64;
    gload16(&actB[aBase[0] + k0], &As[kt][aLds[0]]);
    gload16(&actB[aBase[1] + k0], &As[kt][aLds[1]]);
    gload16(&actB[aBase[2] + k0], &As[kt][aLds[2]]);
    gload16(&actB[aBase[3] + k0], &As[kt][aLds[3]]);
    gload16(&WB[bBase[0] + k0], &Ws[kt][bLds[0]]);
    gload16(&WB[bBase[1] + k0], &Ws[kt][bLds[1]]);
  }

  int bR = 0, bS = 2;
  for (int kt = 0; kt < NT; ++kt) {
    const int kp = kbase + (kt + 2) * 64;
    const bool st = (kt + 2 < NT);
    if (st) {
      gload16(&actB[aBase[0] + kp], &As[bS][aLds[0]]);
      gload16(&actB[aBase[1] + kp], &As[bS][aLds[1]]);
      gload16(&WB[bBase[0] + kp], &Ws[bS][bLds[0]]);
    }
    if (kt < NT - 2)       asm volatile("s_waitcnt vmcnt(9)" ::: "memory");
    else if (kt == NT - 2) asm volatile("s_waitcnt vmcnt(6)" ::: "memory");
    else                   asm volatile("s_waitcnt vmcnt(0)" ::: "memory");
    asm volatile("s_barrier" ::: "memory");

    const bf16* Ab = As[bR];
    const bf16* Wb = Ws[bR];
    u32x4 a[4][2], b0[2][2];
#pragma unroll
    for (int f = 0; f < 4; f++)
#pragma unroll
      for (int s = 0; s < 2; s++) {
        const int row = wr * 64 + f * 16 + lr;
        a[f][s] = *(const u32x4*)&Ab[row * 64 + ((s * 4 + lg) ^ (row & 7)) * 8];
      }
#pragma unroll
    for (int j = 0; j < 2; j++)
#pragma unroll
      for (int s = 0; s < 2; s++) {
        const int row = wc * 64 + j * 16 + lr;
        b0[j][s] = *(const u32x4*)&Wb[row * 64 + ((s * 4 + lg) ^ (row & 7)) * 8];
      }
    __builtin_amdgcn_s_setprio(1);
#pragma unroll
    for (int f = 0; f < 4; f++)
#pragma unroll
      for (int j = 0; j < 2; j++) {
        mfma_bf16(acc[f][j], a[f][0], b0[j][0]);
        mfma_bf16(acc[f][j], a[f][1], b0[j][1]);
      }
    __builtin_amdgcn_s_setprio(0);

    if (st) {
      gload16(&actB[aBase[2] + kp], &As[bS][aLds[2]]);
      gload16(&actB[aBase[3] + kp], &As[bS][aLds[3]]);
      gload16(&WB[bBase[1] + kp], &Ws[bS][bLds[1]]);
    }
    u32x4 b1[2][2];
#pragma unroll
    for (int j = 0; j < 2; j++)
#pragma unroll
      for (int s = 0; s < 2; s++) {
        const int row = wc * 64 + (2 + j) * 16 + lr;
        b1[j][s] = *(const u32x4*)&Wb[row * 64 + ((s * 4 + lg) ^ (row & 7)) * 8];
      }
    __builtin_amdgcn_s_setprio(1);
#pragma unroll
    for (int f = 0; f < 4; f++)
#pragma unroll
      for (int j = 0; j < 2; j++) {
        mfma_bf16(acc[f][2 + j], a[f][0], b1[j][0]);
        mfma_bf16(acc[f][2 + j], a[f][1], b1[j][1]);
      }
    __builtin_amdgcn_s_setprio(0);
    asm volatile("s_waitcnt lgkmcnt(0)" ::: "memory");
    asm volatile("s_barrier" ::: "memory");
    bR = (bR == 2) ? 0 : bR + 1;
    bS = (bS == 2) ? 0 : bS + 1;
  }

#pragma unroll
  for (int i = 0; i < 4; i++) {
#pragma unroll
    for (int r = 0; r < 4; r++) {
      const int m = wr * 64 + i * 16 + lg * 4 + r;
      const int t = perm[tt + m];
      if (t < 0) continue;
#pragma unroll
      for (int j = 0; j < 4; j++) {
        const int col = ot + wc * 64 + j * 16 + lr;
        const float v = acc[i][j][r];
        if (EPI == 0) {
          const bf16 vb = __float2bfloat16(v);
          if (col < D_INNER) outx[(size_t)t * D_INNER + col] = vb;
          else outz[(size_t)t * D_INNER + (col - D_INNER)] = vb;
        } else {
          out0[((size_t)kz * NTOK + t) * D_MODEL + col] = v;
        }
      }
    }
  }
}

__global__ __launch_bounds__(512) void k_inproj(const bf16* actB, const int* perm, const int* ids,
                                                const bf16* WB, bf16* outx, bf16* outz) {
  gemmP_body<D_MODEL, 2 * D_INNER, 1, 0>(actB, perm, ids, WB, outx, outz, nullptr);
}
__global__ __launch_bounds__(512) void k_outproj(const bf16* actB, const int* perm, const int* ids,
                                                 const bf16* WB, float* out0) {
  gemmP_body<D_INNER, D_MODEL, 2, 1>(actB, perm, ids, WB, nullptr, nullptr, out0);
}

// ---- 128x128-tile single-buffer GEMM (x_dbl projection, split-K=8)
__global__ __launch_bounds__(256) void k_xdblg(const bf16* __restrict__ actB,
                                               const int* __restrict__ perm,
                                               const int* __restrict__ ids,
                                               const bf16* __restrict__ WB,
                                               float* __restrict__ out0) {
  constexpr int KDIM = D_INNER, NW = XDBL, LDO = XDBL, KSPLIT = 8;
  constexpr int KLEN = KDIM / KSPLIT;
  __shared__ bf16 As[128 * 64];
  __shared__ bf16 Ws[128 * 64];
  __shared__ int permL[128];
  const int tid = threadIdx.x;
  const int bx = blockIdx.x, by = blockIdx.y;

  const int ot = 0;
  const int kz = bx;
  const int kbase = kz * KLEN;
  const int tt = by * 128;

  if (tid < 128) permL[tid] = perm[tt + tid];

  const int lane = tid & 63, w = tid >> 6;
  const int wr = w >> 1, wc = w & 1;
  const int lr = lane & 15, lg = lane >> 4;

  const int t00 = perm[tt];
  const int eu = (t00 >= 0) ? ids[t00] : 0;
  const size_t wexp = (size_t)eu * NW * KDIM;

  const int srow = w * 32 + (lane >> 3);
  const int scol = (lane & 7) * 8;
  size_t abase[4], bbase[4];
  int ldsoff[4];
#pragma unroll
  for (int v = 0; v < 4; v++) {
    const int row = srow + v * 8;
    int ta = perm[tt + row];
    if (ta < 0) ta = 0;
    abase[v] = (size_t)ta * KDIM + scol;
    int orow = ot + row;
    orow = (orow < NW) ? orow : (NW - 1);
    bbase[v] = wexp + (size_t)orow * KDIM + scol;
    ldsoff[v] = (w * 32 + v * 8) * 64;
  }

  f32x4 acc[4][4];
#pragma unroll
  for (int i = 0; i < 4; i++)
#pragma unroll
    for (int j = 0; j < 4; j++) acc[i][j] = (f32x4){0.f, 0.f, 0.f, 0.f};

  for (int k0 = kbase; k0 < kbase + KLEN; k0 += 64) {
#pragma unroll
    for (int v = 0; v < 4; v++) {
      gload16(&actB[abase[v] + k0], &As[ldsoff[v]]);
      gload16(&WB[bbase[v] + k0], &Ws[ldsoff[v]]);
    }
    __syncthreads();
#pragma unroll
    for (int ks = 0; ks < 64; ks += 32) {
      u32x4 a[4], b[4];
#pragma unroll
      for (int f = 0; f < 4; f++)
        a[f] = *(const u32x4*)&As[(wr * 64 + f * 16 + lr) * 64 + ks + lg * 8];
#pragma unroll
      for (int f = 0; f < 4; f++)
        b[f] = *(const u32x4*)&Ws[(wc * 64 + f * 16 + lr) * 64 + ks + lg * 8];
#pragma unroll
      for (int i = 0; i < 4; i++)
#pragma unroll
        for (int j = 0; j < 4; j++) mfma_bf16(acc[i][j], a[i], b[j]);
    }
    __syncthreads();
  }

#pragma unroll
  for (int i = 0; i < 4; i++) {
#pragma unroll
    for (int r = 0; r < 4; r++) {
      const int m = wr * 64 + i * 16 + lg * 4 + r;
      const int t = permL[m];
      if (t < 0) continue;
#pragma unroll
      for (int j = 0; j < 4; j++) {
        const int col = ot + wc * 64 + j * 16 + lr;
        if (col < NW) out0[((size_t)kz * NTOK + t) * LDO + col] = acc[i][j][r];
      }
    }
  }
}

// ---- dt projection: LDS-tiled fp32 SIMT GEMM, K=64.
// Block = 64 perm-sorted tokens x 64 channels; 256 threads; 4x4 micro-tile.
// X and W staged in LDS (65-pad: 2-way bank aliasing, free). No per-thread
// arrays -> no spill; no wave-uniformity assumptions.
__global__ __launch_bounds__(256) void k_dtv(const float* __restrict__ xdbl,
                                             const int* __restrict__ perm,
                                             const int* __restrict__ ids,
                                             const float* __restrict__ Wdt,
                                             const float* __restrict__ bdt,
                                             bf16* __restrict__ dtB) {
  __shared__ float Xs[64][65];
  __shared__ float Ws[64][65];
  __shared__ int permL[64];
  const int tid = threadIdx.x;
  const int tt = blockIdx.y * 64;
  const int cb = blockIdx.x * 64;
  if (tid < 64) permL[tid] = perm[tt + tid];
  const int t0 = perm[tt];
  const int e = (t0 >= 0) ? ids[t0] : 0;
  {
    const int r = tid >> 2, q = (tid & 3) * 16;  // row 0..63, 16-float quarter
    int ta = perm[tt + r];
    if (ta < 0) ta = 0;
    const float* xsrc = &xdbl[(size_t)ta * XDBL + q];
    const float* wsrc = &Wdt[((size_t)e * D_INNER + cb + r) * DT_RANK + q];
#pragma unroll
    for (int u = 0; u < 4; u++) {
      float4 xv = *(const float4*)&xsrc[u * 4];
      float4 wv = *(const float4*)&wsrc[u * 4];
      *(float4*)&Xs[r][q + u * 4] = xv;
      *(float4*)&Ws[r][q + u * 4] = wv;
    }
  }
  __syncthreads();
  const int tl = (tid & 15) * 4;   // token group
  const int cl = (tid >> 4) * 4;   // channel group
  float acc[4][4] = {};
#pragma unroll
  for (int k4 = 0; k4 < 16; k4++) {
    float4 xv[4], wv[4];
#pragma unroll
    for (int i = 0; i < 4; i++) xv[i] = *(const float4*)&Xs[tl + i][k4 * 4];
#pragma unroll
    for (int j = 0; j < 4; j++) wv[j] = *(const float4*)&Ws[cl + j][k4 * 4];
#pragma unroll
    for (int i = 0; i < 4; i++)
#pragma unroll
      for (int j = 0; j < 4; j++) {
        acc[i][j] = fmaf(xv[i].x, wv[j].x, acc[i][j]);
        acc[i][j] = fmaf(xv[i].y, wv[j].y, acc[i][j]);
        acc[i][j] = fmaf(xv[i].z, wv[j].z, acc[i][j]);
        acc[i][j] = fmaf(xv[i].w, wv[j].w, acc[i][j]);
      }
  }
#pragma unroll
  for (int i = 0; i < 4; i++) {
    const int t = permL[tl + i];
    if (t < 0) continue;
    __align__(8) bf16 ov[4];
#pragma unroll
    for (int j = 0; j < 4; j++)
      ov[j] = __float2bfloat16(softplusf(acc[i][j] + bdt[e * D_INNER + cb + cl + j]));
    *(uint2*)&dtB[(size_t)t * D_INNER + cb + cl] = *(const uint2*)ov;
  }
}

// ---- reduce xdbl split-K partials -> xdbl fp32
__global__ __launch_bounds__(256) void k_xred(const float* __restrict__ part,
                                              float* __restrict__ xdbl) {
  const int i = blockIdx.x * 256 + threadIdx.x;
  float s = 0.f;
#pragma unroll
  for (int k = 0; k < 8; k++) s += part[(size_t)k * NTOK * XDBL + i];
  xdbl[i] = s;
}

// ---- reduce out-proj split-K partials (2x) -> final fp32 output
__global__ __launch_bounds__(256) void k_ored2(const float* __restrict__ part,
                                               float* __restrict__ out) {
  const size_t base = ((size_t)blockIdx.x * 256 + threadIdx.x) * 4;
  constexpr size_t NM = (size_t)NTOK * D_MODEL;
  float4 s = *(const float4*)&part[base];
  float4 p = *(const float4*)&part[NM + base];
  s.x += p.x; s.y += p.y; s.z += p.z; s.w += p.w;
  *(float4*)&out[base] = s;
}

// ---- depthwise causal conv + SiLU; bf16 in, bf16 out
__global__ __launch_bounds__(256) void k_conv(const bf16* __restrict__ xrawB,
                                              const float* __restrict__ cw,
                                              const float* __restrict__ cb,
                                              bf16* __restrict__ xB) {
  int idx = blockIdx.x * 256 + threadIdx.x;
  int c = idx & (D_INNER - 1);
  int t = idx >> 11;
  int l = t & (SEQLEN - 1);
  int b = t >> 11;
  float acc = cb[c];
#pragma unroll
  for (int k = 0; k < D_CONV; k++) {
    int ll = l + k - (D_CONV - 1);
    if (ll >= 0)
      acc = fmaf(cw[c * D_CONV + k],
                 __bfloat162float(xrawB[((size_t)(b * SEQLEN + ll)) * D_INNER + c]), acc);
  }
  xB[(size_t)idx] = __float2bfloat16(siluf(acc));
}

// ---- scan pass A: per-chunk local scan -> F, Sdt
__global__ __launch_bounds__(256) void k_scan_part(const bf16* __restrict__ xB,
                                                   const bf16* __restrict__ dtB,
                                                   const float* __restrict__ xdbl,
                                                   const float* __restrict__ A_log,
                                                   float* __restrict__ F,
                                                   float* __restrict__ Sdt) {
  __shared__ float Bs[LC][D_STATE];
  const int tid = threadIdx.x;
  const int j = blockIdx.y;
  const int ch = blockIdx.x * 256 + tid;
  const int b = ch >> 11, c = ch & (D_INNER - 1);
  const int t0 = (b << 11) + j * LC;
  {
    int l = tid >> 2, q = (tid & 3) * 4;
    *(float4*)&Bs[l][q] = *(const float4*)&xdbl[(size_t)(t0 + l) * XDBL + DT_RANK + q];
  }
  float Ar[D_STATE];
#pragma unroll
  for (int n4 = 0; n4 < 4; n4++) {
    float4 a = *(const float4*)&A_log[(size_t)c * D_STATE + n4 * 4];
    Ar[n4 * 4 + 0] = -__expf(a.x); Ar[n4 * 4 + 1] = -__expf(a.y);
    Ar[n4 * 4 + 2] = -__expf(a.z); Ar[n4 * 4 + 3] = -__expf(a.w);
  }
  __syncthreads();
  float st[D_STATE];
#pragma unroll
  for (int n = 0; n < D_STATE; n++) st[n] = 0.f;
  float sdt = 0.f;
  float dtc = __bfloat162float(dtB[(size_t)t0 * D_INNER + c]);
  float xc = __bfloat162float(xB[(size_t)t0 * D_INNER + c]);
  for (int l = 0; l < LC; l++) {
    float dtn = 0.f, xn = 0.f;
    if (l < LC - 1) {
      dtn = __bfloat162float(dtB[(size_t)(t0 + l + 1) * D_INNER + c]);
      xn = __bfloat162float(xB[(size_t)(t0 + l + 1) * D_INNER + c]);
    }
    const float dtx = dtc * xc;
    sdt += dtc;
#pragma unroll
    for (int n = 0; n < D_STATE; n++) {
      float dA = __expf(dtc * Ar[n]);
      st[n] = fmaf(st[n], dA, dtx * Bs[l][n]);
    }
    dtc = dtn; xc = xn;
  }
  const size_t fb = ((size_t)j * NTOK + ch) * D_STATE;
#pragma unroll
  for (int n4 = 0; n4 < 4; n4++)
    *(float4*)&F[fb + n4 * 4] = make_float4(st[n4 * 4], st[n4 * 4 + 1], st[n4 * 4 + 2], st[n4 * 4 + 3]);
  Sdt[(size_t)j * NTOK + ch] = sdt;
}

// ---- scan pass B: sequential combine across chunks -> s0 per chunk
__global__ __launch_bounds__(256) void k_combine(const float* __restrict__ F,
                                                 const float* __restrict__ Sdt,
                                                 const float* __restrict__ A_log,
                                                 float* __restrict__ s0) {
  const int gid = blockIdx.x * 256 + threadIdx.x;
  const int ch = gid >> 4, n = gid & 15, c = ch & (D_INNER - 1);
  const float Ar = -__expf(A_log[(size_t)c * D_STATE + n]);
  float s = 0.f;
  for (int j = 0; j < NC; j++) {
    s0[((size_t)j * NTOK + ch) * D_STATE + n] = s;
    s = fmaf(s, __expf(Ar * Sdt[(size_t)j * NTOK + ch]), F[((size_t)j * NTOK + ch) * D_STATE + n]);
  }
}

// ---- scan pass C: recompute with s0, emit yB = bf16((scan + x*D) * silu(z))
__global__ __launch_bounds__(256) void k_scan_fin(const bf16* __restrict__ xB,
                                                  const bf16* __restrict__ dtB,
                                                  const float* __restrict__ xdbl,
                                                  const bf16* __restrict__ zB,
                                                  const float* __restrict__ A_log,
                                                  const float* __restrict__ Dp,
                                                  const float* __restrict__ s0,
                                                  bf16* __restrict__ ybuf) {
  __shared__ float Bs[LC][D_STATE];
  __shared__ float Cs[LC][D_STATE];
  const int tid = threadIdx.x;
  const int j = blockIdx.y;
  const int ch = blockIdx.x * 256 + tid;
  const int b = ch >> 11, c = ch & (D_INNER - 1);
  const int t0 = (b << 11) + j * LC;
  {
    int l = tid >> 2, q = (tid & 3) * 4;
    *(float4*)&Bs[l][q] = *(const float4*)&xdbl[(size_t)(t0 + l) * XDBL + DT_RANK + q];
    *(float4*)&Cs[l][q] = *(const float4*)&xdbl[(size_t)(t0 + l) * XDBL + DT_RANK + D_STATE + q];
  }
  float Ar[D_STATE];
#pragma unroll
  for (int n4 = 0; n4 < 4; n4++) {
    float4 a = *(const float4*)&A_log[(size_t)c * D_STATE + n4 * 4];
    Ar[n4 * 4 + 0] = -__expf(a.x); Ar[n4 * 4 + 1] = -__expf(a.y);
    Ar[n4 * 4 + 2] = -__expf(a.z); Ar[n4 * 4 + 3] = -__expf(a.w);
  }
  __syncthreads();
  float st[D_STATE];
  const size_t sb = ((size_t)j * NTOK + ch) * D_STATE;
#pragma unroll
  for (int n4 = 0; n4 < 4; n4++) {
    float4 s = *(const float4*)&s0[sb + n4 * 4];
    st[n4 * 4 + 0] = s.x; st[n4 * 4 + 1] = s.y; st[n4 * 4 + 2] = s.z; st[n4 * 4 + 3] = s.w;
  }
  const float Dc = Dp[c];
  float dtc = __bfloat162float(dtB[(size_t)t0 * D_INNER + c]);
  float xc = __bfloat162float(xB[(size_t)t0 * D_INNER + c]);
  for (int l = 0; l < LC; l++) {
    float dtn = 0.f, xn = 0.f;
    if (l < LC - 1) {
      dtn = __bfloat162float(dtB[(size_t)(t0 + l + 1) * D_INNER + c]);
      xn = __bfloat162float(xB[(size_t)(t0 + l + 1) * D_INNER + c]);
    }
    const float zv = __bfloat162float(zB[(size_t)(t0 + l) * D_INNER + c]);
    const float dtx = dtc * xc;
    float y = 0.f;
#pragma unroll
    for (int n = 0; n < D_STATE; n++) {
      float dA = __expf(dtc * Ar[n]);
      st[n] = fmaf(st[n], dA, dtx * Bs[l][n]);
      y = fmaf(st[n], Cs[l][n], y);
    }
    float yv = fmaf(xc, Dc, y);
    ybuf[(size_t)(t0 + l) * D_INNER + c] = __float2bfloat16(yv * siluf(zv));
    dtc = dtn; xc = xn;
  }
}

extern "C" void kernel_launch(void* const* d_in, const int* in_sizes, int n_in,
                              void* d_out, int out_size, void* d_ws, size_t ws_size,
                              hipStream_t stream) {
  const float* h = (const float*)d_in[0];
  const int* ids = (const int*)d_in[1];
  const float* Win = (const float*)d_in[2];
  const float* cw = (const float*)d_in[3];
  const float* cb = (const float*)d_in[4];
  const float* Wx = (const float*)d_in[5];
  const float* Wdt = (const float*)d_in[6];
  const float* bdt = (const float*)d_in[7];
  const float* Alog = (const float*)d_in[8];
  const float* Dp = (const float*)d_in[9];
  const float* Wout = (const float*)d_in[10];
  float* out = (float*)d_out;

  const size_t NTD = (size_t)NTOK * D_INNER;  // 8,388,608
  float* ws = (float*)d_ws;
  float* slot0 = ws + 0 * NTD;   // hB (bf16) -> dtbB (bf16)
  float* slot1 = ws + 1 * NTD;   // zB (bf16); later out-proj partials (2x fp32 = slot1)
  float* slot2 = ws + 2 * NTD;   // WinB (bf16) -> xdbl split-K partials (fp32)
  float* slot3 = ws + 3 * NTD;   // xrawB (bf16) -> F (fp32) -> yB (bf16)
  size_t cur = 4 * NTD;
  float* xdbl_p = ws + cur; cur += (size_t)NTOK * XDBL;
  float* sdt_p = ws + cur; cur += (size_t)NC * NTOK;
  int* perm = (int*)(ws + cur); cur += PADTOT;
  bf16* xB = (bf16*)(ws + cur); cur += NTD / 2;
  bf16* WoB = (bf16*)(ws + cur); cur += CVT_WO / 2;
  bf16* WxB = (bf16*)(ws + cur); cur += CVT_WX / 2;
  bf16* WdtB = (bf16*)(ws + cur); cur += CVT_WDT / 2;  // unused (dt uses fp32 W)

  bf16* hB = (bf16*)slot0;        // dead after in-proj
  bf16* dtbB = (bf16*)slot0;      // written by k_dtv (after hB dead)
  bf16* zB = (bf16*)slot1;        // dead after scan_fin
  bf16* WinB = (bf16*)slot2;      // dead after in-proj
  float* part = slot2;            // xdbl split-K partials (dead after xred)
  float* part2 = slot1;           // out-proj partials: 2*NTOK*D_MODEL fp32 = slot1 exactly
  bf16* xrawB = (bf16*)slot3;     // dead after conv
  float* F = slot3;               // dead after combine
  bf16* yB = (bf16*)slot3;
  float* s0 = (float*)d_out;      // scratch in d_out, dead after scan_fin

  k_perm<<<1, 1024, 0, stream>>>(ids, perm);
  k_cvtall<<<CVT_TOT / 8 / 256, 256, 0, stream>>>(h, Win, Wx, Wdt, Wout, hB, WinB, WxB, WdtB, WoB);
  k_inproj<<<dim3(32, 17), 512, 0, stream>>>(hB, perm, ids, WinB, xrawB, zB);
  k_conv<<<NTD / 256, 256, 0, stream>>>(xrawB, cw, cb, xB);
  k_xdblg<<<dim3(8, 34), 256, 0, stream>>>(xB, perm, ids, WxB, part);
  k_xred<<<NTOK * XDBL / 256, 256, 0, stream>>>(part, xdbl_p);
  k_dtv<<<dim3(32, PADTOT / 64), 256, 0, stream>>>(xdbl_p, perm, ids, Wdt, bdt, dtbB);
  k_scan_part<<<dim3(16, NC), 256, 0, stream>>>(xB, dtbB, xdbl_p, Alog, F, sdt_p);
  k_combine<<<256, 256, 0, stream>>>(F, sdt_p, Alog, s0);
  k_scan_fin<<<dim3(16, NC), 256, 0, stream>>>(xB, dtbB, xdbl_p, zB, Alog, Dp, s0, yB);
  k_outproj<<<dim3(16, 17), 512, 0, stream>>>(yB, perm, ids, WoB, part2);
  k_ored2<<<NTOK * D_MODEL / 4 / 256, 256, 0, stream>>>(part2, out);
}

// Round 14
// 321.554 us; speedup vs baseline: 1.2710x; 1.2710x over previous
//
#include <hip/hip_runtime.h>
#include <hip/hip_bf16.h>
#include <math.h>

#define B_SZ 2
#define SEQLEN 2048
#define D_MODEL 1024
#define D_INNER 2048
#define D_STATE 16
#define D_CONV 4
#define DT_RANK 64
#define NTOK (B_SZ * SEQLEN)      /* 4096 */
#define XDBL 96                   /* DT_RANK + 2*D_STATE */
#define NC 32                     /* scan chunks */
#define LC 64                     /* chunk length */
#define PADTOT (17 * 256)         /* padded perm length (256-aligned experts) */

typedef float f32x4 __attribute__((ext_vector_type(4)));
typedef unsigned int u32x4 __attribute__((ext_vector_type(4)));
typedef __hip_bfloat16 bf16;

__device__ __forceinline__ float siluf(float v) { return v / (1.f + __expf(-v)); }
// fast softplus: log1pf is a slow libm call (~490 VALU-cyc measured via R11 dtg);
// __logf/__expf are single HW transcendentals. |err| <= ~1e-7 rel, fine vs threshold.
__device__ __forceinline__ float softplusf(float v) {
  return (v > 20.f) ? v : __logf(1.f + __expf(v));
}

__device__ __forceinline__ void mfma_bf16(f32x4& acc, u32x4 a, u32x4 b) {
  asm volatile("v_mfma_f32_16x16x32_bf16 %0, %1, %2, %0" : "+v"(acc) : "v"(a), "v"(b));
}

__device__ __forceinline__ void gload16(const bf16* g, bf16* l) {
  __builtin_amdgcn_global_load_lds(
      (const __attribute__((address_space(1))) unsigned int*)g,
      (__attribute__((address_space(3))) unsigned int*)l, 16, 0, 0);
}

// ---- token partition by expert, padded so every 256-row panel is pure-expert.
__global__ __launch_bounds__(1024) void k_perm(const int* __restrict__ ids, int* __restrict__ perm) {
  __shared__ int sc[1024];
  const int tid = threadIdx.x;
  int loc[4];
  int cnt = 0;
#pragma unroll
  for (int q = 0; q < 4; q++) {
    loc[q] = ids[tid * 4 + q];
    cnt += (loc[q] == 0);
  }
  sc[tid] = cnt;
  __syncthreads();
  for (int off = 1; off < 1024; off <<= 1) {
    int v = sc[tid];
    int u = (tid >= off) ? sc[tid - off] : 0;
    __syncthreads();
    sc[tid] = v + u;
    __syncthreads();
  }
  const int N0 = sc[1023];
  const int m0 = (N0 + 255) & ~255;
  const int N1 = NTOK - N0;
  for (int idx = tid; idx < PADTOT; idx += 1024)
    if ((idx >= N0 && idx < m0) || idx >= m0 + N1) perm[idx] = -1;
  int zb = sc[tid] - cnt;
#pragma unroll
  for (int q = 0; q < 4; q++) {
    int t = tid * 4 + q;
    if (loc[q] == 0) { perm[zb] = t; zb++; }
    else             { perm[m0 + (t - zb)] = t; }
  }
}

// ---- fused fp32 -> bf16 conversion of h and all GEMM weights
#define CVT_H   (NTOK * D_MODEL)
#define CVT_WIN (2 * 2 * D_INNER * D_MODEL)
#define CVT_WX  (2 * XDBL * D_INNER)
#define CVT_WDT (2 * D_INNER * DT_RANK)
#define CVT_WO  (2 * D_MODEL * D_INNER)
#define CVT_TOT (CVT_H + CVT_WIN + CVT_WX + CVT_WDT + CVT_WO)
__global__ __launch_bounds__(256) void k_cvtall(const float* __restrict__ h,
                                                const float* __restrict__ Win,
                                                const float* __restrict__ Wx,
                                                const float* __restrict__ Wdt,
                                                const float* __restrict__ Wout,
                                                bf16* __restrict__ hB, bf16* __restrict__ WinB,
                                                bf16* __restrict__ WxB, bf16* __restrict__ WdtB,
                                                bf16* __restrict__ WoB) {
  size_t i = ((size_t)blockIdx.x * 256 + threadIdx.x) * 8;
  const float* src; bf16* dst; size_t off;
  if (i < CVT_H)                          { src = h;    dst = hB;   off = i; }
  else if (i < CVT_H + CVT_WIN)           { src = Win;  dst = WinB; off = i - CVT_H; }
  else if (i < CVT_H + CVT_WIN + CVT_WX)  { src = Wx;   dst = WxB;  off = i - CVT_H - CVT_WIN; }
  else if (i < CVT_TOT - CVT_WO)          { src = Wdt;  dst = WdtB; off = i - CVT_H - CVT_WIN - CVT_WX; }
  else                                    { src = Wout; dst = WoB;  off = i - (CVT_TOT - CVT_WO); }
  float4 f0 = *(const float4*)&src[off];
  float4 f1 = *(const float4*)&src[off + 4];
  __align__(16) bf16 tmp[8];
  tmp[0] = __float2bfloat16(f0.x); tmp[1] = __float2bfloat16(f0.y);
  tmp[2] = __float2bfloat16(f0.z); tmp[3] = __float2bfloat16(f0.w);
  tmp[4] = __float2bfloat16(f1.x); tmp[5] = __float2bfloat16(f1.y);
  tmp[6] = __float2bfloat16(f1.z); tmp[7] = __float2bfloat16(f1.w);
  *(u32x4*)&dst[off] = *(const u32x4*)tmp;
}

// ---- deep-pipelined 256x128 GEMM body (ring-3 LDS, depth-2 prefetch, counted vmcnt).
// EPI 0 (in-proj): col<2048 -> outx bf16; else -> outz bf16.
// EPI 1 (out-proj): fp32 partial out0[(kz*NTOK+t)*D_MODEL + col].
template <int KDIM, int NW, int KSPLIT, int EPI>
__device__ __forceinline__ void gemmP_body(const bf16* __restrict__ actB,
                                           const int* __restrict__ perm,
                                           const int* __restrict__ ids,
                                           const bf16* __restrict__ WB,
                                           bf16* __restrict__ outx,
                                           bf16* __restrict__ outz,
                                           float* __restrict__ out0) {
  constexpr int KLEN = KDIM / KSPLIT;
  constexpr int NT = KLEN / 64;      // 16 for both instances
  constexpr int NCOL = (EPI == 1) ? (D_MODEL / 128) : 0;
  __shared__ bf16 As[3][256 * 64];   // 96 KB
  __shared__ bf16 Ws[3][128 * 64];   // 48 KB
  const int tid = threadIdx.x;

  const int gx = gridDim.x;
  const int nwg = gx * gridDim.y;
  const int fid = blockIdx.y * gx + blockIdx.x;
  const int q8 = nwg >> 3;
  const int swz = (fid & 7) * q8 + (fid >> 3);
  const int bx = swz % gx, by = swz / gx;
  const int ot = (KSPLIT > 1) ? (bx % NCOL) * 128 : bx * 128;
  const int kz = (KSPLIT > 1) ? bx / NCOL : 0;
  const int kbase = kz * KLEN;
  const int tt = by * 256;

  const int lane = tid & 63, w = tid >> 6;  // 8 waves
  const int wr = w >> 1, wc = w & 1;        // 4M x 2N
  const int lr = lane & 15, lg = lane >> 4;

  const int t00 = perm[tt];
  const int eu = (t00 >= 0) ? ids[t00] : 0;
  const size_t wexp = (size_t)eu * NW * KDIM;

  const int kswz = ((lane & 7) ^ ((lane >> 3) & 7)) * 8;
  size_t aBase[4]; int aLds[4];
  size_t bBase[2]; int bLds[2];
#pragma unroll
  for (int v = 0; v < 4; v++) {
    const int row = w * 32 + v * 8 + (lane >> 3);
    int ta = perm[tt + row]; if (ta < 0) ta = 0;
    aBase[v] = (size_t)ta * KDIM + kswz;
    aLds[v] = (w * 32 + v * 8) * 64;
  }
#pragma unroll
  for (int v = 0; v < 2; v++) {
    const int row = w * 16 + v * 8 + (lane >> 3);
    bBase[v] = wexp + (size_t)(ot + row) * KDIM + kswz;
    bLds[v] = (w * 16 + v * 8) * 64;
  }

  f32x4 acc[4][4];
#pragma unroll
  for (int i = 0; i < 4; i++)
#pragma unroll
    for (int j = 0; j < 4; j++) acc[i][j] = (f32x4){0.f, 0.f, 0.f, 0.f};

#pragma unroll
  for (int kt = 0; kt < 2; kt++) {
    const int k0 = kbase + kt * 64;
    gload16(&actB[aBase[0] + k0], &As[kt][aLds[0]]);
    gload16(&actB[aBase[1] + k0], &As[kt][aLds[1]]);
    gload16(&actB[aBase[2] + k0], &As[kt][aLds[2]]);
    gload16(&actB[aBase[3] + k0], &As[kt][aLds[3]]);
    gload16(&WB[bBase[0] + k0], &Ws[kt][bLds[0]]);
    gload16(&WB[bBase[1] + k0], &Ws[kt][bLds[1]]);
  }

  int bR = 0, bS = 2;
  for (int kt = 0; kt < NT; ++kt) {
    const int kp = kbase + (kt + 2) * 64;
    const bool st = (kt + 2 < NT);
    if (st) {
      gload16(&actB[aBase[0] + kp], &As[bS][aLds[0]]);
      gload16(&actB[aBase[1] + kp], &As[bS][aLds[1]]);
      gload16(&WB[bBase[0] + kp], &Ws[bS][bLds[0]]);
    }
    if (kt < NT - 2)       asm volatile("s_waitcnt vmcnt(9)" ::: "memory");
    else if (kt == NT - 2) asm volatile("s_waitcnt vmcnt(6)" ::: "memory");
    else                   asm volatile("s_waitcnt vmcnt(0)" ::: "memory");
    asm volatile("s_barrier" ::: "memory");

    const bf16* Ab = As[bR];
    const bf16* Wb = Ws[bR];
    u32x4 a[4][2], b0[2][2];
#pragma unroll
    for (int f = 0; f < 4; f++)
#pragma unroll
      for (int s = 0; s < 2; s++) {
        const int row = wr * 64 + f * 16 + lr;
        a[f][s] = *(const u32x4*)&Ab[row * 64 + ((s * 4 + lg) ^ (row & 7)) * 8];
      }
#pragma unroll
    for (int j = 0; j < 2; j++)
#pragma unroll
      for (int s = 0; s < 2; s++) {
        const int row = wc * 64 + j * 16 + lr;
        b0[j][s] = *(const u32x4*)&Wb[row * 64 + ((s * 4 + lg) ^ (row & 7)) * 8];
      }
    __builtin_amdgcn_s_setprio(1);
#pragma unroll
    for (int f = 0; f < 4; f++)
#pragma unroll
      for (int j = 0; j < 2; j++) {
        mfma_bf16(acc[f][j], a[f][0], b0[j][0]);
        mfma_bf16(acc[f][j], a[f][1], b0[j][1]);
      }
    __builtin_amdgcn_s_setprio(0);

    if (st) {
      gload16(&actB[aBase[2] + kp], &As[bS][aLds[2]]);
      gload16(&actB[aBase[3] + kp], &As[bS][aLds[3]]);
      gload16(&WB[bBase[1] + kp], &Ws[bS][bLds[1]]);
    }
    u32x4 b1[2][2];
#pragma unroll
    for (int j = 0; j < 2; j++)
#pragma unroll
      for (int s = 0; s < 2; s++) {
        const int row = wc * 64 + (2 + j) * 16 + lr;
        b1[j][s] = *(const u32x4*)&Wb[row * 64 + ((s * 4 + lg) ^ (row & 7)) * 8];
      }
    __builtin_amdgcn_s_setprio(1);
#pragma unroll
    for (int f = 0; f < 4; f++)
#pragma unroll
      for (int j = 0; j < 2; j++) {
        mfma_bf16(acc[f][2 + j], a[f][0], b1[j][0]);
        mfma_bf16(acc[f][2 + j], a[f][1], b1[j][1]);
      }
    __builtin_amdgcn_s_setprio(0);
    asm volatile("s_waitcnt lgkmcnt(0)" ::: "memory");
    asm volatile("s_barrier" ::: "memory");
    bR = (bR == 2) ? 0 : bR + 1;
    bS = (bS == 2) ? 0 : bS + 1;
  }

#pragma unroll
  for (int i = 0; i < 4; i++) {
#pragma unroll
    for (int r = 0; r < 4; r++) {
      const int m = wr * 64 + i * 16 + lg * 4 + r;
      const int t = perm[tt + m];
      if (t < 0) continue;
#pragma unroll
      for (int j = 0; j < 4; j++) {
        const int col = ot + wc * 64 + j * 16 + lr;
        const float v = acc[i][j][r];
        if (EPI == 0) {
          const bf16 vb = __float2bfloat16(v);
          if (col < D_INNER) outx[(size_t)t * D_INNER + col] = vb;
          else outz[(size_t)t * D_INNER + (col - D_INNER)] = vb;
        } else {
          out0[((size_t)kz * NTOK + t) * D_MODEL + col] = v;
        }
      }
    }
  }
}

__global__ __launch_bounds__(512) void k_inproj(const bf16* actB, const int* perm, const int* ids,
                                                const bf16* WB, bf16* outx, bf16* outz) {
  gemmP_body<D_MODEL, 2 * D_INNER, 1, 0>(actB, perm, ids, WB, outx, outz, nullptr);
}
__global__ __launch_bounds__(512) void k_outproj(const bf16* actB, const int* perm, const int* ids,
                                                 const bf16* WB, float* out0) {
  gemmP_body<D_INNER, D_MODEL, 2, 1>(actB, perm, ids, WB, nullptr, nullptr, out0);
}

// ---- 128x128-tile single-buffer GEMM (x_dbl projection, split-K=8)
__global__ __launch_bounds__(256) void k_xdblg(const bf16* __restrict__ actB,
                                               const int* __restrict__ perm,
                                               const int* __restrict__ ids,
                                               const bf16* __restrict__ WB,
                                               float* __restrict__ out0) {
  constexpr int KDIM = D_INNER, NW = XDBL, LDO = XDBL, KSPLIT = 8;
  constexpr int KLEN = KDIM / KSPLIT;
  __shared__ bf16 As[128 * 64];
  __shared__ bf16 Ws[128 * 64];
  __shared__ int permL[128];
  const int tid = threadIdx.x;
  const int bx = blockIdx.x, by = blockIdx.y;

  const int ot = 0;
  const int kz = bx;
  const int kbase = kz * KLEN;
  const int tt = by * 128;

  if (tid < 128) permL[tid] = perm[tt + tid];

  const int lane = tid & 63, w = tid >> 6;
  const int wr = w >> 1, wc = w & 1;
  const int lr = lane & 15, lg = lane >> 4;

  const int t00 = perm[tt];
  const int eu = (t00 >= 0) ? ids[t00] : 0;
  const size_t wexp = (size_t)eu * NW * KDIM;

  const int srow = w * 32 + (lane >> 3);
  const int scol = (lane & 7) * 8;
  size_t abase[4], bbase[4];
  int ldsoff[4];
#pragma unroll
  for (int v = 0; v < 4; v++) {
    const int row = srow + v * 8;
    int ta = perm[tt + row];
    if (ta < 0) ta = 0;
    abase[v] = (size_t)ta * KDIM + scol;
    int orow = ot + row;
    orow = (orow < NW) ? orow : (NW - 1);
    bbase[v] = wexp + (size_t)orow * KDIM + scol;
    ldsoff[v] = (w * 32 + v * 8) * 64;
  }

  f32x4 acc[4][4];
#pragma unroll
  for (int i = 0; i < 4; i++)
#pragma unroll
    for (int j = 0; j < 4; j++) acc[i][j] = (f32x4){0.f, 0.f, 0.f, 0.f};

  for (int k0 = kbase; k0 < kbase + KLEN; k0 += 64) {
#pragma unroll
    for (int v = 0; v < 4; v++) {
      gload16(&actB[abase[v] + k0], &As[ldsoff[v]]);
      gload16(&WB[bbase[v] + k0], &Ws[ldsoff[v]]);
    }
    __syncthreads();
#pragma unroll
    for (int ks = 0; ks < 64; ks += 32) {
      u32x4 a[4], b[4];
#pragma unroll
      for (int f = 0; f < 4; f++)
        a[f] = *(const u32x4*)&As[(wr * 64 + f * 16 + lr) * 64 + ks + lg * 8];
#pragma unroll
      for (int f = 0; f < 4; f++)
        b[f] = *(const u32x4*)&Ws[(wc * 64 + f * 16 + lr) * 64 + ks + lg * 8];
#pragma unroll
      for (int i = 0; i < 4; i++)
#pragma unroll
        for (int j = 0; j < 4; j++) mfma_bf16(acc[i][j], a[i], b[j]);
    }
    __syncthreads();
  }

#pragma unroll
  for (int i = 0; i < 4; i++) {
#pragma unroll
    for (int r = 0; r < 4; r++) {
      const int m = wr * 64 + i * 16 + lg * 4 + r;
      const int t = permL[m];
      if (t < 0) continue;
#pragma unroll
      for (int j = 0; j < 4; j++) {
        const int col = ot + wc * 64 + j * 16 + lr;
        if (col < NW) out0[((size_t)kz * NTOK + t) * LDO + col] = acc[i][j][r];
      }
    }
  }
}

// ---- dt projection: LDS-tiled fp32 SIMT GEMM, K=64.
// Block = 64 perm-sorted tokens x 64 channels; 256 threads; 4x4 micro-tile.
// __launch_bounds__(256,4) caps VGPR at 128 (R13's full unroll hit 256 + spill);
// #pragma unroll 2 keeps LDS-load live ranges short. Fast softplus.
__global__ __launch_bounds__(256, 4) void k_dtv(const float* __restrict__ xdbl,
                                                const int* __restrict__ perm,
                                                const int* __restrict__ ids,
                                                const float* __restrict__ Wdt,
                                                const float* __restrict__ bdt,
                                                bf16* __restrict__ dtB) {
  __shared__ float Xs[64][65];
  __shared__ float Ws[64][65];
  __shared__ int permL[64];
  const int tid = threadIdx.x;
  const int tt = blockIdx.y * 64;
  const int cb = blockIdx.x * 64;
  if (tid < 64) permL[tid] = perm[tt + tid];
  const int t0 = perm[tt];
  const int e = (t0 >= 0) ? ids[t0] : 0;
  {
    const int r = tid >> 2, q = (tid & 3) * 16;  // row 0..63, 16-float quarter
    int ta = perm[tt + r];
    if (ta < 0) ta = 0;
    const float* xsrc = &xdbl[(size_t)ta * XDBL + q];
    const float* wsrc = &Wdt[((size_t)e * D_INNER + cb + r) * DT_RANK + q];
#pragma unroll
    for (int u = 0; u < 4; u++) {
      float4 xv = *(const float4*)&xsrc[u * 4];
      float4 wv = *(const float4*)&wsrc[u * 4];
      *(float4*)&Xs[r][q + u * 4] = xv;
      *(float4*)&Ws[r][q + u * 4] = wv;
    }
  }
  __syncthreads();
  const int tl = (tid & 15) * 4;   // token group
  const int cl = (tid >> 4) * 4;   // channel group
  float acc[4][4] = {};
#pragma unroll 2
  for (int k4 = 0; k4 < 16; k4++) {
    float4 xv[4], wv[4];
#pragma unroll
    for (int i = 0; i < 4; i++) xv[i] = *(const float4*)&Xs[tl + i][k4 * 4];
#pragma unroll
    for (int j = 0; j < 4; j++) wv[j] = *(const float4*)&Ws[cl + j][k4 * 4];
#pragma unroll
    for (int i = 0; i < 4; i++)
#pragma unroll
      for (int j = 0; j < 4; j++) {
        acc[i][j] = fmaf(xv[i].x, wv[j].x, acc[i][j]);
        acc[i][j] = fmaf(xv[i].y, wv[j].y, acc[i][j]);
        acc[i][j] = fmaf(xv[i].z, wv[j].z, acc[i][j]);
        acc[i][j] = fmaf(xv[i].w, wv[j].w, acc[i][j]);
      }
  }
#pragma unroll
  for (int i = 0; i < 4; i++) {
    const int t = permL[tl + i];
    if (t < 0) continue;
    __align__(8) bf16 ov[4];
#pragma unroll
    for (int j = 0; j < 4; j++)
      ov[j] = __float2bfloat16(softplusf(acc[i][j] + bdt[e * D_INNER + cb + cl + j]));
    *(uint2*)&dtB[(size_t)t * D_INNER + cb + cl] = *(const uint2*)ov;
  }
}

// ---- reduce xdbl split-K partials -> xdbl fp32
__global__ __launch_bounds__(256) void k_xred(const float* __restrict__ part,
                                              float* __restrict__ xdbl) {
  const int i = blockIdx.x * 256 + threadIdx.x;
  float s = 0.f;
#pragma unroll
  for (int k = 0; k < 8; k++) s += part[(size_t)k * NTOK * XDBL + i];
  xdbl[i] = s;
}

// ---- reduce out-proj split-K partials (2x) -> final fp32 output
__global__ __launch_bounds__(256) void k_ored2(const float* __restrict__ part,
                                               float* __restrict__ out) {
  const size_t base = ((size_t)blockIdx.x * 256 + threadIdx.x) * 4;
  constexpr size_t NM = (size_t)NTOK * D_MODEL;
  float4 s = *(const float4*)&part[base];
  float4 p = *(const float4*)&part[NM + base];
  s.x += p.x; s.y += p.y; s.z += p.z; s.w += p.w;
  *(float4*)&out[base] = s;
}

// ---- depthwise causal conv + SiLU; bf16 in, bf16 out
__global__ __launch_bounds__(256) void k_conv(const bf16* __restrict__ xrawB,
                                              const float* __restrict__ cw,
                                              const float* __restrict__ cb,
                                              bf16* __restrict__ xB) {
  int idx = blockIdx.x * 256 + threadIdx.x;
  int c = idx & (D_INNER - 1);
  int t = idx >> 11;
  int l = t & (SEQLEN - 1);
  int b = t >> 11;
  float acc = cb[c];
#pragma unroll
  for (int k = 0; k < D_CONV; k++) {
    int ll = l + k - (D_CONV - 1);
    if (ll >= 0)
      acc = fmaf(cw[c * D_CONV + k],
                 __bfloat162float(xrawB[((size_t)(b * SEQLEN + ll)) * D_INNER + c]), acc);
  }
  xB[(size_t)idx] = __float2bfloat16(siluf(acc));
}

// ---- scan pass A: per-chunk local scan -> F, Sdt
__global__ __launch_bounds__(256) void k_scan_part(const bf16* __restrict__ xB,
                                                   const bf16* __restrict__ dtB,
                                                   const float* __restrict__ xdbl,
                                                   const float* __restrict__ A_log,
                                                   float* __restrict__ F,
                                                   float* __restrict__ Sdt) {
  __shared__ float Bs[LC][D_STATE];
  const int tid = threadIdx.x;
  const int j = blockIdx.y;
  const int ch = blockIdx.x * 256 + tid;
  const int b = ch >> 11, c = ch & (D_INNER - 1);
  const int t0 = (b << 11) + j * LC;
  {
    int l = tid >> 2, q = (tid & 3) * 4;
    *(float4*)&Bs[l][q] = *(const float4*)&xdbl[(size_t)(t0 + l) * XDBL + DT_RANK + q];
  }
  float Ar[D_STATE];
#pragma unroll
  for (int n4 = 0; n4 < 4; n4++) {
    float4 a = *(const float4*)&A_log[(size_t)c * D_STATE + n4 * 4];
    Ar[n4 * 4 + 0] = -__expf(a.x); Ar[n4 * 4 + 1] = -__expf(a.y);
    Ar[n4 * 4 + 2] = -__expf(a.z); Ar[n4 * 4 + 3] = -__expf(a.w);
  }
  __syncthreads();
  float st[D_STATE];
#pragma unroll
  for (int n = 0; n < D_STATE; n++) st[n] = 0.f;
  float sdt = 0.f;
  float dtc = __bfloat162float(dtB[(size_t)t0 * D_INNER + c]);
  float xc = __bfloat162float(xB[(size_t)t0 * D_INNER + c]);
  for (int l = 0; l < LC; l++) {
    float dtn = 0.f, xn = 0.f;
    if (l < LC - 1) {
      dtn = __bfloat162float(dtB[(size_t)(t0 + l + 1) * D_INNER + c]);
      xn = __bfloat162float(xB[(size_t)(t0 + l + 1) * D_INNER + c]);
    }
    const float dtx = dtc * xc;
    sdt += dtc;
#pragma unroll
    for (int n = 0; n < D_STATE; n++) {
      float dA = __expf(dtc * Ar[n]);
      st[n] = fmaf(st[n], dA, dtx * Bs[l][n]);
    }
    dtc = dtn; xc = xn;
  }
  const size_t fb = ((size_t)j * NTOK + ch) * D_STATE;
#pragma unroll
  for (int n4 = 0; n4 < 4; n4++)
    *(float4*)&F[fb + n4 * 4] = make_float4(st[n4 * 4], st[n4 * 4 + 1], st[n4 * 4 + 2], st[n4 * 4 + 3]);
  Sdt[(size_t)j * NTOK + ch] = sdt;
}

// ---- scan pass B: sequential combine across chunks -> s0 per chunk
__global__ __launch_bounds__(256) void k_combine(const float* __restrict__ F,
                                                 const float* __restrict__ Sdt,
                                                 const float* __restrict__ A_log,
                                                 float* __restrict__ s0) {
  const int gid = blockIdx.x * 256 + threadIdx.x;
  const int ch = gid >> 4, n = gid & 15, c = ch & (D_INNER - 1);
  const float Ar = -__expf(A_log[(size_t)c * D_STATE + n]);
  float s = 0.f;
  for (int j = 0; j < NC; j++) {
    s0[((size_t)j * NTOK + ch) * D_STATE + n] = s;
    s = fmaf(s, __expf(Ar * Sdt[(size_t)j * NTOK + ch]), F[((size_t)j * NTOK + ch) * D_STATE + n]);
  }
}

// ---- scan pass C: recompute with s0, emit yB = bf16((scan + x*D) * silu(z))
__global__ __launch_bounds__(256) void k_scan_fin(const bf16* __restrict__ xB,
                                                  const bf16* __restrict__ dtB,
                                                  const float* __restrict__ xdbl,
                                                  const bf16* __restrict__ zB,
                                                  const float* __restrict__ A_log,
                                                  const float* __restrict__ Dp,
                                                  const float* __restrict__ s0,
                                                  bf16* __restrict__ ybuf) {
  __shared__ float Bs[LC][D_STATE];
  __shared__ float Cs[LC][D_STATE];
  const int tid = threadIdx.x;
  const int j = blockIdx.y;
  const int ch = blockIdx.x * 256 + tid;
  const int b = ch >> 11, c = ch & (D_INNER - 1);
  const int t0 = (b << 11) + j * LC;
  {
    int l = tid >> 2, q = (tid & 3) * 4;
    *(float4*)&Bs[l][q] = *(const float4*)&xdbl[(size_t)(t0 + l) * XDBL + DT_RANK + q];
    *(float4*)&Cs[l][q] = *(const float4*)&xdbl[(size_t)(t0 + l) * XDBL + DT_RANK + D_STATE + q];
  }
  float Ar[D_STATE];
#pragma unroll
  for (int n4 = 0; n4 < 4; n4++) {
    float4 a = *(const float4*)&A_log[(size_t)c * D_STATE + n4 * 4];
    Ar[n4 * 4 + 0] = -__expf(a.x); Ar[n4 * 4 + 1] = -__expf(a.y);
    Ar[n4 * 4 + 2] = -__expf(a.z); Ar[n4 * 4 + 3] = -__expf(a.w);
  }
  __syncthreads();
  float st[D_STATE];
  const size_t sb = ((size_t)j * NTOK + ch) * D_STATE;
#pragma unroll
  for (int n4 = 0; n4 < 4; n4++) {
    float4 s = *(const float4*)&s0[sb + n4 * 4];
    st[n4 * 4 + 0] = s.x; st[n4 * 4 + 1] = s.y; st[n4 * 4 + 2] = s.z; st[n4 * 4 + 3] = s.w;
  }
  const float Dc = Dp[c];
  float dtc = __bfloat162float(dtB[(size_t)t0 * D_INNER + c]);
  float xc = __bfloat162float(xB[(size_t)t0 * D_INNER + c]);
  for (int l = 0; l < LC; l++) {
    float dtn = 0.f, xn = 0.f;
    if (l < LC - 1) {
      dtn = __bfloat162float(dtB[(size_t)(t0 + l + 1) * D_INNER + c]);
      xn = __bfloat162float(xB[(size_t)(t0 + l + 1) * D_INNER + c]);
    }
    const float zv = __bfloat162float(zB[(size_t)(t0 + l) * D_INNER + c]);
    const float dtx = dtc * xc;
    float y = 0.f;
#pragma unroll
    for (int n = 0; n < D_STATE; n++) {
      float dA = __expf(dtc * Ar[n]);
      st[n] = fmaf(st[n], dA, dtx * Bs[l][n]);
      y = fmaf(st[n], Cs[l][n], y);
    }
    float yv = fmaf(xc, Dc, y);
    ybuf[(size_t)(t0 + l) * D_INNER + c] = __float2bfloat16(yv * siluf(zv));
    dtc = dtn; xc = xn;
  }
}

extern "C" void kernel_launch(void* const* d_in, const int* in_sizes, int n_in,
                              void* d_out, int out_size, void* d_ws, size_t ws_size,
                              hipStream_t stream) {
  const float* h = (const float*)d_in[0];
  const int* ids = (const int*)d_in[1];
  const float* Win = (const float*)d_in[2];
  const float* cw = (const float*)d_in[3];
  const float* cb = (const float*)d_in[4];
  const float* Wx = (const float*)d_in[5];
  const float* Wdt = (const float*)d_in[6];
  const float* bdt = (const float*)d_in[7];
  const float* Alog = (const float*)d_in[8];
  const float* Dp = (const float*)d_in[9];
  const float* Wout = (const float*)d_in[10];
  float* out = (float*)d_out;

  const size_t NTD = (size_t)NTOK * D_INNER;  // 8,388,608
  float* ws = (float*)d_ws;
  float* slot0 = ws + 0 * NTD;   // hB (bf16) -> dtbB (bf16)
  float* slot1 = ws + 1 * NTD;   // zB (bf16); later out-proj partials (2x fp32 = slot1)
  float* slot2 = ws + 2 * NTD;   // WinB (bf16) -> xdbl split-K partials (fp32)
  float* slot3 = ws + 3 * NTD;   // xrawB (bf16) -> F (fp32) -> yB (bf16)
  size_t cur = 4 * NTD;
  float* xdbl_p = ws + cur; cur += (size_t)NTOK * XDBL;
  float* sdt_p = ws + cur; cur += (size_t)NC * NTOK;
  int* perm = (int*)(ws + cur); cur += PADTOT;
  bf16* xB = (bf16*)(ws + cur); cur += NTD / 2;
  bf16* WoB = (bf16*)(ws + cur); cur += CVT_WO / 2;
  bf16* WxB = (bf16*)(ws + cur); cur += CVT_WX / 2;
  bf16* WdtB = (bf16*)(ws + cur); cur += CVT_WDT / 2;  // unused (dt uses fp32 W)

  bf16* hB = (bf16*)slot0;        // dead after in-proj
  bf16* dtbB = (bf16*)slot0;      // written by k_dtv (after hB dead)
  bf16* zB = (bf16*)slot1;        // dead after scan_fin
  bf16* WinB = (bf16*)slot2;      // dead after in-proj
  float* part = slot2;            // xdbl split-K partials (dead after xred)
  float* part2 = slot1;           // out-proj partials: 2*NTOK*D_MODEL fp32 = slot1 exactly
  bf16* xrawB = (bf16*)slot3;     // dead after conv
  float* F = slot3;               // dead after combine
  bf16* yB = (bf16*)slot3;
  float* s0 = (float*)d_out;      // scratch in d_out, dead after scan_fin

  k_perm<<<1, 1024, 0, stream>>>(ids, perm);
  k_cvtall<<<CVT_TOT / 8 / 256, 256, 0, stream>>>(h, Win, Wx, Wdt, Wout, hB, WinB, WxB, WdtB, WoB);
  k_inproj<<<dim3(32, 17), 512, 0, stream>>>(hB, perm, ids, WinB, xrawB, zB);
  k_conv<<<NTD / 256, 256, 0, stream>>>(xrawB, cw, cb, xB);
  k_xdblg<<<dim3(8, 34), 256, 0, stream>>>(xB, perm, ids, WxB, part);
  k_xred<<<NTOK * XDBL / 256, 256, 0, stream>>>(part, xdbl_p);
  k_dtv<<<dim3(32, PADTOT / 64), 256, 0, stream>>>(xdbl_p, perm, ids, Wdt, bdt, dtbB);
  k_scan_part<<<dim3(16, NC), 256, 0, stream>>>(xB, dtbB, xdbl_p, Alog, F, sdt_p);
  k_combine<<<256, 256, 0, stream>>>(F, sdt_p, Alog, s0);
  k_scan_fin<<<dim3(16, NC), 256, 0, stream>>>(xB, dtbB, xdbl_p, zB, Alog, Dp, s0, yB);
  k_outproj<<<dim3(16, 17), 512, 0, stream>>>(yB, perm, ids, WoB, part2);
  k_ored2<<<NTOK * D_MODEL / 4 / 256, 256, 0, stream>>>(part2, out);
}

// Round 15
// 303.115 us; speedup vs baseline: 1.3484x; 1.0608x over previous
//
#include <hip/hip_runtime.h>
#include <hip/hip_bf16.h>
#include <math.h>

#define B_SZ 2
#define SEQLEN 2048
#define D_MODEL 1024
#define D_INNER 2048
#define D_STATE 16
#define D_CONV 4
#define DT_RANK 64
#define NTOK (B_SZ * SEQLEN)      /* 4096 */
#define XDBL 96                   /* DT_RANK + 2*D_STATE */
#define NC 32                     /* scan chunks */
#define LC 64                     /* chunk length */
#define PADTOT (17 * 256)         /* padded perm length (256-aligned experts) */

typedef float f32x4 __attribute__((ext_vector_type(4)));
typedef unsigned int u32x4 __attribute__((ext_vector_type(4)));
typedef __hip_bfloat16 bf16;

__device__ __forceinline__ float siluf(float v) { return v / (1.f + __expf(-v)); }
// fast softplus: log1pf is a slow libm call; __logf/__expf are HW transcendentals.
__device__ __forceinline__ float softplusf(float v) {
  return (v > 20.f) ? v : __logf(1.f + __expf(v));
}

__device__ __forceinline__ void mfma_bf16(f32x4& acc, u32x4 a, u32x4 b) {
  asm volatile("v_mfma_f32_16x16x32_bf16 %0, %1, %2, %0" : "+v"(acc) : "v"(a), "v"(b));
}

__device__ __forceinline__ void gload16(const bf16* g, bf16* l) {
  __builtin_amdgcn_global_load_lds(
      (const __attribute__((address_space(1))) unsigned int*)g,
      (__attribute__((address_space(3))) unsigned int*)l, 16, 0, 0);
}

// ---- token partition by expert, padded so every 256-row panel is pure-expert.
__global__ __launch_bounds__(1024) void k_perm(const int* __restrict__ ids, int* __restrict__ perm) {
  __shared__ int sc[1024];
  const int tid = threadIdx.x;
  int loc[4];
  int cnt = 0;
#pragma unroll
  for (int q = 0; q < 4; q++) {
    loc[q] = ids[tid * 4 + q];
    cnt += (loc[q] == 0);
  }
  sc[tid] = cnt;
  __syncthreads();
  for (int off = 1; off < 1024; off <<= 1) {
    int v = sc[tid];
    int u = (tid >= off) ? sc[tid - off] : 0;
    __syncthreads();
    sc[tid] = v + u;
    __syncthreads();
  }
  const int N0 = sc[1023];
  const int m0 = (N0 + 255) & ~255;
  const int N1 = NTOK - N0;
  for (int idx = tid; idx < PADTOT; idx += 1024)
    if ((idx >= N0 && idx < m0) || idx >= m0 + N1) perm[idx] = -1;
  int zb = sc[tid] - cnt;
#pragma unroll
  for (int q = 0; q < 4; q++) {
    int t = tid * 4 + q;
    if (loc[q] == 0) { perm[zb] = t; zb++; }
    else             { perm[m0 + (t - zb)] = t; }
  }
}

// ---- fused fp32 -> bf16 conversion of h and all GEMM weights
#define CVT_H   (NTOK * D_MODEL)
#define CVT_WIN (2 * 2 * D_INNER * D_MODEL)
#define CVT_WX  (2 * XDBL * D_INNER)
#define CVT_WDT (2 * D_INNER * DT_RANK)
#define CVT_WO  (2 * D_MODEL * D_INNER)
#define CVT_TOT (CVT_H + CVT_WIN + CVT_WX + CVT_WDT + CVT_WO)
__global__ __launch_bounds__(256) void k_cvtall(const float* __restrict__ h,
                                                const float* __restrict__ Win,
                                                const float* __restrict__ Wx,
                                                const float* __restrict__ Wdt,
                                                const float* __restrict__ Wout,
                                                bf16* __restrict__ hB, bf16* __restrict__ WinB,
                                                bf16* __restrict__ WxB, bf16* __restrict__ WdtB,
                                                bf16* __restrict__ WoB) {
  size_t i = ((size_t)blockIdx.x * 256 + threadIdx.x) * 8;
  const float* src; bf16* dst; size_t off;
  if (i < CVT_H)                          { src = h;    dst = hB;   off = i; }
  else if (i < CVT_H + CVT_WIN)           { src = Win;  dst = WinB; off = i - CVT_H; }
  else if (i < CVT_H + CVT_WIN + CVT_WX)  { src = Wx;   dst = WxB;  off = i - CVT_H - CVT_WIN; }
  else if (i < CVT_TOT - CVT_WO)          { src = Wdt;  dst = WdtB; off = i - CVT_H - CVT_WIN - CVT_WX; }
  else                                    { src = Wout; dst = WoB;  off = i - (CVT_TOT - CVT_WO); }
  float4 f0 = *(const float4*)&src[off];
  float4 f1 = *(const float4*)&src[off + 4];
  __align__(16) bf16 tmp[8];
  tmp[0] = __float2bfloat16(f0.x); tmp[1] = __float2bfloat16(f0.y);
  tmp[2] = __float2bfloat16(f0.z); tmp[3] = __float2bfloat16(f0.w);
  tmp[4] = __float2bfloat16(f1.x); tmp[5] = __float2bfloat16(f1.y);
  tmp[6] = __float2bfloat16(f1.z); tmp[7] = __float2bfloat16(f1.w);
  *(u32x4*)&dst[off] = *(const u32x4*)tmp;
}

// ---- 256x256-tile GEMM body, ring-2 LDS double-buffer, counted vmcnt, 8 waves 2Mx4N,
// XOR LDS swizzle (pre-swizzled global source + swizzled ds_read), row-chunk XCD swizzle.
// 1 block/CU (128KB LDS); staged bytes minimized vs 256x128.
// EPI 0 (in-proj): col<2048 -> outx bf16; else -> outz bf16.
// EPI 1 (out-proj): fp32 partial out0[(kz*NTOK+t)*D_MODEL + col].
template <int KDIM, int NW, int KSPLIT, int EPI>
__device__ __forceinline__ void gemmQ_body(const bf16* __restrict__ actB,
                                           const int* __restrict__ perm,
                                           const int* __restrict__ ids,
                                           const bf16* __restrict__ WB,
                                           bf16* __restrict__ outx,
                                           bf16* __restrict__ outz,
                                           float* __restrict__ out0) {
  constexpr int KLEN = KDIM / KSPLIT;
  constexpr int NT = KLEN / 64;     // 16 for both instances
  constexpr int NCOL = NW / 256;
  __shared__ bf16 As[2][256 * 64];  // 64 KB
  __shared__ bf16 Ws[2][256 * 64];  // 64 KB
  const int tid = threadIdx.x;

  const int gx = gridDim.x;
  const int nwg = gx * gridDim.y;
  const int fid = blockIdx.y * gx + blockIdx.x;
  const int q8 = nwg >> 3;
  const int swz = (fid & 7) * q8 + (fid >> 3);
  const int bx = swz % gx, by = swz / gx;   // consecutive swz -> same row panel (A reuse)
  const int ot = (KSPLIT > 1) ? (bx % NCOL) * 256 : bx * 256;
  const int kz = (KSPLIT > 1) ? bx / NCOL : 0;
  const int kbase = kz * KLEN;
  const int tt = by * 256;

  const int lane = tid & 63, w = tid >> 6;  // 8 waves
  const int wr = w >> 2, wc = w & 3;        // 2M x 4N -> per-wave 128x64
  const int lr = lane & 15, lg = lane >> 4;

  const int t00 = perm[tt];
  const int eu = (t00 >= 0) ? ids[t00] : 0;
  const size_t wexp = (size_t)eu * NW * KDIM;

  // staging: gload v covers rows [(w*4+v)*8, +8); lane l -> row +(l>>3), swizzled col
  const int srow_l = lane >> 3;
  const int kswz = ((lane & 7) ^ srow_l) * 8;  // pre-swizzled global source column
  size_t aBase[4], bBase[4];
  int ldsE[4];
#pragma unroll
  for (int v = 0; v < 4; v++) {
    const int row = (w * 4 + v) * 8 + srow_l;
    int ta = perm[tt + row];
    if (ta < 0) ta = 0;
    aBase[v] = (size_t)ta * KDIM + kswz;
    bBase[v] = wexp + (size_t)(ot + row) * KDIM + kswz;
    ldsE[v] = (w * 4 + v) * 512;  // wave-uniform LDS element base
  }

  f32x4 acc[8][4];
#pragma unroll
  for (int i = 0; i < 8; i++)
#pragma unroll
    for (int j = 0; j < 4; j++) acc[i][j] = (f32x4){0.f, 0.f, 0.f, 0.f};

  auto STAGE = [&](int buf, int k0) {
#pragma unroll
    for (int v = 0; v < 4; v++) {
      gload16(&actB[aBase[v] + k0], &As[buf][ldsE[v]]);
      gload16(&WB[bBase[v] + k0], &Ws[buf][ldsE[v]]);
    }
  };

  STAGE(0, kbase);
  int cur = 0;
  for (int kt = 0; kt < NT; ++kt) {
    if (kt + 1 < NT) {
      STAGE(cur ^ 1, kbase + (kt + 1) * 64);            // +8 loads (16 outstanding)
      asm volatile("s_waitcnt vmcnt(8)" ::: "memory");  // cur's 8 landed
    } else {
      asm volatile("s_waitcnt vmcnt(0)" ::: "memory");
    }
    asm volatile("s_barrier" ::: "memory");
    const bf16* Ab = As[cur];
    const bf16* Wb = Ws[cur];
#pragma unroll
    for (int s = 0; s < 2; s++) {  // two K=32 slices
      u32x4 a[8], b[4];
#pragma unroll
      for (int f = 0; f < 8; f++) {
        const int row = wr * 128 + f * 16 + lr;
        a[f] = *(const u32x4*)&Ab[row * 64 + ((s * 4 + lg) ^ (row & 7)) * 8];
      }
#pragma unroll
      for (int j = 0; j < 4; j++) {
        const int row = wc * 64 + j * 16 + lr;
        b[j] = *(const u32x4*)&Wb[row * 64 + ((s * 4 + lg) ^ (row & 7)) * 8];
      }
      __builtin_amdgcn_s_setprio(1);
#pragma unroll
      for (int f = 0; f < 8; f++)
#pragma unroll
        for (int j = 0; j < 4; j++) mfma_bf16(acc[f][j], a[f], b[j]);
      __builtin_amdgcn_s_setprio(0);
    }
    asm volatile("s_waitcnt lgkmcnt(0)" ::: "memory");
    asm volatile("s_barrier" ::: "memory");
    cur ^= 1;
  }

  // epilogue: C row = lg*4 + r (within 16), col = lr
#pragma unroll
  for (int i = 0; i < 8; i++) {
#pragma unroll
    for (int r = 0; r < 4; r++) {
      const int m = wr * 128 + i * 16 + lg * 4 + r;
      const int t = perm[tt + m];
      if (t < 0) continue;
#pragma unroll
      for (int j = 0; j < 4; j++) {
        const int col = ot + wc * 64 + j * 16 + lr;
        const float v = acc[i][j][r];
        if (EPI == 0) {
          const bf16 vb = __float2bfloat16(v);
          if (col < D_INNER) outx[(size_t)t * D_INNER + col] = vb;
          else outz[(size_t)t * D_INNER + (col - D_INNER)] = vb;
        } else {
          out0[((size_t)kz * NTOK + t) * D_MODEL + col] = v;
        }
      }
    }
  }
}

__global__ __launch_bounds__(512) void k_inproj(const bf16* actB, const int* perm, const int* ids,
                                                const bf16* WB, bf16* outx, bf16* outz) {
  gemmQ_body<D_MODEL, 2 * D_INNER, 1, 0>(actB, perm, ids, WB, outx, outz, nullptr);
}
__global__ __launch_bounds__(512) void k_outproj(const bf16* actB, const int* perm, const int* ids,
                                                 const bf16* WB, float* out0) {
  gemmQ_body<D_INNER, D_MODEL, 2, 1>(actB, perm, ids, WB, nullptr, nullptr, out0);
}

// ---- 128x128-tile single-buffer GEMM (x_dbl projection, split-K=8)
__global__ __launch_bounds__(256) void k_xdblg(const bf16* __restrict__ actB,
                                               const int* __restrict__ perm,
                                               const int* __restrict__ ids,
                                               const bf16* __restrict__ WB,
                                               float* __restrict__ out0) {
  constexpr int KDIM = D_INNER, NW = XDBL, LDO = XDBL, KSPLIT = 8;
  constexpr int KLEN = KDIM / KSPLIT;
  __shared__ bf16 As[128 * 64];
  __shared__ bf16 Ws[128 * 64];
  __shared__ int permL[128];
  const int tid = threadIdx.x;
  const int bx = blockIdx.x, by = blockIdx.y;

  const int ot = 0;
  const int kz = bx;
  const int kbase = kz * KLEN;
  const int tt = by * 128;

  if (tid < 128) permL[tid] = perm[tt + tid];

  const int lane = tid & 63, w = tid >> 6;
  const int wr = w >> 1, wc = w & 1;
  const int lr = lane & 15, lg = lane >> 4;

  const int t00 = perm[tt];
  const int eu = (t00 >= 0) ? ids[t00] : 0;
  const size_t wexp = (size_t)eu * NW * KDIM;

  const int srow = w * 32 + (lane >> 3);
  const int scol = (lane & 7) * 8;
  size_t abase[4], bbase[4];
  int ldsoff[4];
#pragma unroll
  for (int v = 0; v < 4; v++) {
    const int row = srow + v * 8;
    int ta = perm[tt + row];
    if (ta < 0) ta = 0;
    abase[v] = (size_t)ta * KDIM + scol;
    int orow = ot + row;
    orow = (orow < NW) ? orow : (NW - 1);
    bbase[v] = wexp + (size_t)orow * KDIM + scol;
    ldsoff[v] = (w * 32 + v * 8) * 64;
  }

  f32x4 acc[4][4];
#pragma unroll
  for (int i = 0; i < 4; i++)
#pragma unroll
    for (int j = 0; j < 4; j++) acc[i][j] = (f32x4){0.f, 0.f, 0.f, 0.f};

  for (int k0 = kbase; k0 < kbase + KLEN; k0 += 64) {
#pragma unroll
    for (int v = 0; v < 4; v++) {
      gload16(&actB[abase[v] + k0], &As[ldsoff[v]]);
      gload16(&WB[bbase[v] + k0], &Ws[ldsoff[v]]);
    }
    __syncthreads();
#pragma unroll
    for (int ks = 0; ks < 64; ks += 32) {
      u32x4 a[4], b[4];
#pragma unroll
      for (int f = 0; f < 4; f++)
        a[f] = *(const u32x4*)&As[(wr * 64 + f * 16 + lr) * 64 + ks + lg * 8];
#pragma unroll
      for (int f = 0; f < 4; f++)
        b[f] = *(const u32x4*)&Ws[(wc * 64 + f * 16 + lr) * 64 + ks + lg * 8];
#pragma unroll
      for (int i = 0; i < 4; i++)
#pragma unroll
        for (int j = 0; j < 4; j++) mfma_bf16(acc[i][j], a[i], b[j]);
    }
    __syncthreads();
  }

#pragma unroll
  for (int i = 0; i < 4; i++) {
#pragma unroll
    for (int r = 0; r < 4; r++) {
      const int m = wr * 64 + i * 16 + lg * 4 + r;
      const int t = permL[m];
      if (t < 0) continue;
#pragma unroll
      for (int j = 0; j < 4; j++) {
        const int col = ot + wc * 64 + j * 16 + lr;
        if (col < NW) out0[((size_t)kz * NTOK + t) * LDO + col] = acc[i][j][r];
      }
    }
  }
}

// ---- dt projection: LDS-tiled fp32 SIMT GEMM, K=64 (R14-proven: capped regs, fast softplus).
__global__ __launch_bounds__(256, 4) void k_dtv(const float* __restrict__ xdbl,
                                                const int* __restrict__ perm,
                                                const int* __restrict__ ids,
                                                const float* __restrict__ Wdt,
                                                const float* __restrict__ bdt,
                                                bf16* __restrict__ dtB) {
  __shared__ float Xs[64][65];
  __shared__ float Ws[64][65];
  __shared__ int permL[64];
  const int tid = threadIdx.x;
  const int tt = blockIdx.y * 64;
  const int cb = blockIdx.x * 64;
  if (tid < 64) permL[tid] = perm[tt + tid];
  const int t0 = perm[tt];
  const int e = (t0 >= 0) ? ids[t0] : 0;
  {
    const int r = tid >> 2, q = (tid & 3) * 16;
    int ta = perm[tt + r];
    if (ta < 0) ta = 0;
    const float* xsrc = &xdbl[(size_t)ta * XDBL + q];
    const float* wsrc = &Wdt[((size_t)e * D_INNER + cb + r) * DT_RANK + q];
#pragma unroll
    for (int u = 0; u < 4; u++) {
      float4 xv = *(const float4*)&xsrc[u * 4];
      float4 wv = *(const float4*)&wsrc[u * 4];
      *(float4*)&Xs[r][q + u * 4] = xv;
      *(float4*)&Ws[r][q + u * 4] = wv;
    }
  }
  __syncthreads();
  const int tl = (tid & 15) * 4;
  const int cl = (tid >> 4) * 4;
  float acc[4][4] = {};
#pragma unroll 2
  for (int k4 = 0; k4 < 16; k4++) {
    float4 xv[4], wv[4];
#pragma unroll
    for (int i = 0; i < 4; i++) xv[i] = *(const float4*)&Xs[tl + i][k4 * 4];
#pragma unroll
    for (int j = 0; j < 4; j++) wv[j] = *(const float4*)&Ws[cl + j][k4 * 4];
#pragma unroll
    for (int i = 0; i < 4; i++)
#pragma unroll
      for (int j = 0; j < 4; j++) {
        acc[i][j] = fmaf(xv[i].x, wv[j].x, acc[i][j]);
        acc[i][j] = fmaf(xv[i].y, wv[j].y, acc[i][j]);
        acc[i][j] = fmaf(xv[i].z, wv[j].z, acc[i][j]);
        acc[i][j] = fmaf(xv[i].w, wv[j].w, acc[i][j]);
      }
  }
#pragma unroll
  for (int i = 0; i < 4; i++) {
    const int t = permL[tl + i];
    if (t < 0) continue;
    __align__(8) bf16 ov[4];
#pragma unroll
    for (int j = 0; j < 4; j++)
      ov[j] = __float2bfloat16(softplusf(acc[i][j] + bdt[e * D_INNER + cb + cl + j]));
    *(uint2*)&dtB[(size_t)t * D_INNER + cb + cl] = *(const uint2*)ov;
  }
}

// ---- reduce xdbl split-K partials -> xdbl fp32
__global__ __launch_bounds__(256) void k_xred(const float* __restrict__ part,
                                              float* __restrict__ xdbl) {
  const int i = blockIdx.x * 256 + threadIdx.x;
  float s = 0.f;
#pragma unroll
  for (int k = 0; k < 8; k++) s += part[(size_t)k * NTOK * XDBL + i];
  xdbl[i] = s;
}

// ---- reduce out-proj split-K partials (2x) -> final fp32 output
__global__ __launch_bounds__(256) void k_ored2(const float* __restrict__ part,
                                               float* __restrict__ out) {
  const size_t base = ((size_t)blockIdx.x * 256 + threadIdx.x) * 4;
  constexpr size_t NM = (size_t)NTOK * D_MODEL;
  float4 s = *(const float4*)&part[base];
  float4 p = *(const float4*)&part[NM + base];
  s.x += p.x; s.y += p.y; s.z += p.z; s.w += p.w;
  *(float4*)&out[base] = s;
}

// ---- depthwise causal conv + SiLU; bf16 in, bf16 out
__global__ __launch_bounds__(256) void k_conv(const bf16* __restrict__ xrawB,
                                              const float* __restrict__ cw,
                                              const float* __restrict__ cb,
                                              bf16* __restrict__ xB) {
  int idx = blockIdx.x * 256 + threadIdx.x;
  int c = idx & (D_INNER - 1);
  int t = idx >> 11;
  int l = t & (SEQLEN - 1);
  int b = t >> 11;
  float acc = cb[c];
#pragma unroll
  for (int k = 0; k < D_CONV; k++) {
    int ll = l + k - (D_CONV - 1);
    if (ll >= 0)
      acc = fmaf(cw[c * D_CONV + k],
                 __bfloat162float(xrawB[((size_t)(b * SEQLEN + ll)) * D_INNER + c]), acc);
  }
  xB[(size_t)idx] = __float2bfloat16(siluf(acc));
}

// ---- scan pass A: per-chunk local scan -> F (bf16), Sdt
__global__ __launch_bounds__(256) void k_scan_part(const bf16* __restrict__ xB,
                                                   const bf16* __restrict__ dtB,
                                                   const float* __restrict__ xdbl,
                                                   const float* __restrict__ A_log,
                                                   bf16* __restrict__ F,
                                                   float* __restrict__ Sdt) {
  __shared__ float Bs[LC][D_STATE];
  const int tid = threadIdx.x;
  const int j = blockIdx.y;
  const int ch = blockIdx.x * 256 + tid;
  const int b = ch >> 11, c = ch & (D_INNER - 1);
  const int t0 = (b << 11) + j * LC;
  {
    int l = tid >> 2, q = (tid & 3) * 4;
    *(float4*)&Bs[l][q] = *(const float4*)&xdbl[(size_t)(t0 + l) * XDBL + DT_RANK + q];
  }
  float Ar[D_STATE];
#pragma unroll
  for (int n4 = 0; n4 < 4; n4++) {
    float4 a = *(const float4*)&A_log[(size_t)c * D_STATE + n4 * 4];
    Ar[n4 * 4 + 0] = -__expf(a.x); Ar[n4 * 4 + 1] = -__expf(a.y);
    Ar[n4 * 4 + 2] = -__expf(a.z); Ar[n4 * 4 + 3] = -__expf(a.w);
  }
  __syncthreads();
  float st[D_STATE];
#pragma unroll
  for (int n = 0; n < D_STATE; n++) st[n] = 0.f;
  float sdt = 0.f;
  float dtc = __bfloat162float(dtB[(size_t)t0 * D_INNER + c]);
  float xc = __bfloat162float(xB[(size_t)t0 * D_INNER + c]);
  for (int l = 0; l < LC; l++) {
    float dtn = 0.f, xn = 0.f;
    if (l < LC - 1) {
      dtn = __bfloat162float(dtB[(size_t)(t0 + l + 1) * D_INNER + c]);
      xn = __bfloat162float(xB[(size_t)(t0 + l + 1) * D_INNER + c]);
    }
    const float dtx = dtc * xc;
    sdt += dtc;
#pragma unroll
    for (int n = 0; n < D_STATE; n++) {
      float dA = __expf(dtc * Ar[n]);
      st[n] = fmaf(st[n], dA, dtx * Bs[l][n]);
    }
    dtc = dtn; xc = xn;
  }
  const size_t fb = ((size_t)j * NTOK + ch) * D_STATE;
  __align__(16) bf16 fv[16];
#pragma unroll
  for (int n = 0; n < D_STATE; n++) fv[n] = __float2bfloat16(st[n]);
  *(u32x4*)&F[fb] = *(const u32x4*)fv;
  *(u32x4*)&F[fb + 8] = *(const u32x4*)(fv + 8);
  Sdt[(size_t)j * NTOK + ch] = sdt;
}

// ---- scan pass B: sequential combine across chunks -> s0 (bf16) per chunk
__global__ __launch_bounds__(256) void k_combine(const bf16* __restrict__ F,
                                                 const float* __restrict__ Sdt,
                                                 const float* __restrict__ A_log,
                                                 bf16* __restrict__ s0) {
  const int gid = blockIdx.x * 256 + threadIdx.x;
  const int ch = gid >> 4, n = gid & 15, c = ch & (D_INNER - 1);
  const float Ar = -__expf(A_log[(size_t)c * D_STATE + n]);
  float s = 0.f;
  for (int j = 0; j < NC; j++) {
    s0[((size_t)j * NTOK + ch) * D_STATE + n] = __float2bfloat16(s);
    s = fmaf(s, __expf(Ar * Sdt[(size_t)j * NTOK + ch]),
             __bfloat162float(F[((size_t)j * NTOK + ch) * D_STATE + n]));
  }
}

// ---- scan pass C: recompute with s0, emit yB = bf16((scan + x*D) * silu(z))
__global__ __launch_bounds__(256) void k_scan_fin(const bf16* __restrict__ xB,
                                                  const bf16* __restrict__ dtB,
                                                  const float* __restrict__ xdbl,
                                                  const bf16* __restrict__ zB,
                                                  const float* __restrict__ A_log,
                                                  const float* __restrict__ Dp,
                                                  const bf16* __restrict__ s0,
                                                  bf16* __restrict__ ybuf) {
  __shared__ float Bs[LC][D_STATE];
  __shared__ float Cs[LC][D_STATE];
  const int tid = threadIdx.x;
  const int j = blockIdx.y;
  const int ch = blockIdx.x * 256 + tid;
  const int b = ch >> 11, c = ch & (D_INNER - 1);
  const int t0 = (b << 11) + j * LC;
  {
    int l = tid >> 2, q = (tid & 3) * 4;
    *(float4*)&Bs[l][q] = *(const float4*)&xdbl[(size_t)(t0 + l) * XDBL + DT_RANK + q];
    *(float4*)&Cs[l][q] = *(const float4*)&xdbl[(size_t)(t0 + l) * XDBL + DT_RANK + D_STATE + q];
  }
  float Ar[D_STATE];
#pragma unroll
  for (int n4 = 0; n4 < 4; n4++) {
    float4 a = *(const float4*)&A_log[(size_t)c * D_STATE + n4 * 4];
    Ar[n4 * 4 + 0] = -__expf(a.x); Ar[n4 * 4 + 1] = -__expf(a.y);
    Ar[n4 * 4 + 2] = -__expf(a.z); Ar[n4 * 4 + 3] = -__expf(a.w);
  }
  __syncthreads();
  float st[D_STATE];
  const size_t sb = ((size_t)j * NTOK + ch) * D_STATE;
#pragma unroll
  for (int n = 0; n < D_STATE; n++) st[n] = __bfloat162float(s0[sb + n]);
  const float Dc = Dp[c];
  float dtc = __bfloat162float(dtB[(size_t)t0 * D_INNER + c]);
  float xc = __bfloat162float(xB[(size_t)t0 * D_INNER + c]);
  for (int l = 0; l < LC; l++) {
    float dtn = 0.f, xn = 0.f;
    if (l < LC - 1) {
      dtn = __bfloat162float(dtB[(size_t)(t0 + l + 1) * D_INNER + c]);
      xn = __bfloat162float(xB[(size_t)(t0 + l + 1) * D_INNER + c]);
    }
    const float zv = __bfloat162float(zB[(size_t)(t0 + l) * D_INNER + c]);
    const float dtx = dtc * xc;
    float y = 0.f;
#pragma unroll
    for (int n = 0; n < D_STATE; n++) {
      float dA = __expf(dtc * Ar[n]);
      st[n] = fmaf(st[n], dA, dtx * Bs[l][n]);
      y = fmaf(st[n], Cs[l][n], y);
    }
    float yv = fmaf(xc, Dc, y);
    ybuf[(size_t)(t0 + l) * D_INNER + c] = __float2bfloat16(yv * siluf(zv));
    dtc = dtn; xc = xn;
  }
}

extern "C" void kernel_launch(void* const* d_in, const int* in_sizes, int n_in,
                              void* d_out, int out_size, void* d_ws, size_t ws_size,
                              hipStream_t stream) {
  const float* h = (const float*)d_in[0];
  const int* ids = (const int*)d_in[1];
  const float* Win = (const float*)d_in[2];
  const float* cw = (const float*)d_in[3];
  const float* cb = (const float*)d_in[4];
  const float* Wx = (const float*)d_in[5];
  const float* Wdt = (const float*)d_in[6];
  const float* bdt = (const float*)d_in[7];
  const float* Alog = (const float*)d_in[8];
  const float* Dp = (const float*)d_in[9];
  const float* Wout = (const float*)d_in[10];
  float* out = (float*)d_out;

  const size_t NTD = (size_t)NTOK * D_INNER;  // 8,388,608
  float* ws = (float*)d_ws;
  float* slot0 = ws + 0 * NTD;   // hB (bf16) -> dtbB (bf16)
  float* slot1 = ws + 1 * NTD;   // zB (bf16); later out-proj partials (2x fp32 = slot1)
  float* slot2 = ws + 2 * NTD;   // WinB (bf16) -> xdbl split-K partials (fp32)
  float* slot3 = ws + 3 * NTD;   // xrawB (bf16) -> F (bf16) -> yB (bf16)
  size_t cur = 4 * NTD;
  float* xdbl_p = ws + cur; cur += (size_t)NTOK * XDBL;
  float* sdt_p = ws + cur; cur += (size_t)NC * NTOK;
  int* perm = (int*)(ws + cur); cur += PADTOT;
  bf16* xB = (bf16*)(ws + cur); cur += NTD / 2;
  bf16* WoB = (bf16*)(ws + cur); cur += CVT_WO / 2;
  bf16* WxB = (bf16*)(ws + cur); cur += CVT_WX / 2;
  bf16* WdtB = (bf16*)(ws + cur); cur += CVT_WDT / 2;  // unused (dt uses fp32 W)

  bf16* hB = (bf16*)slot0;        // dead after in-proj
  bf16* dtbB = (bf16*)slot0;      // written by k_dtv (after hB dead)
  bf16* zB = (bf16*)slot1;        // dead after scan_fin
  bf16* WinB = (bf16*)slot2;      // dead after in-proj
  float* part = slot2;            // xdbl split-K partials (dead after xred)
  float* part2 = slot1;           // out-proj partials: 2*NTOK*D_MODEL fp32 = slot1 exactly
  bf16* xrawB = (bf16*)slot3;     // dead after conv
  bf16* F = (bf16*)slot3;         // bf16 F (4.2MB); dead after combine
  bf16* yB = (bf16*)slot3;
  bf16* s0 = (bf16*)d_out;        // bf16 s0 (4.2MB) scratch in d_out, dead after scan_fin

  k_perm<<<1, 1024, 0, stream>>>(ids, perm);
  k_cvtall<<<CVT_TOT / 8 / 256, 256, 0, stream>>>(h, Win, Wx, Wdt, Wout, hB, WinB, WxB, WdtB, WoB);
  k_inproj<<<dim3(16, 17), 512, 0, stream>>>(hB, perm, ids, WinB, xrawB, zB);
  k_conv<<<NTD / 256, 256, 0, stream>>>(xrawB, cw, cb, xB);
  k_xdblg<<<dim3(8, 34), 256, 0, stream>>>(xB, perm, ids, WxB, part);
  k_xred<<<NTOK * XDBL / 256, 256, 0, stream>>>(part, xdbl_p);
  k_dtv<<<dim3(32, PADTOT / 64), 256, 0, stream>>>(xdbl_p, perm, ids, Wdt, bdt, dtbB);
  k_scan_part<<<dim3(16, NC), 256, 0, stream>>>(xB, dtbB, xdbl_p, Alog, F, sdt_p);
  k_combine<<<256, 256, 0, stream>>>(F, sdt_p, Alog, s0);
  k_scan_fin<<<dim3(16, NC), 256, 0, stream>>>(xB, dtbB, xdbl_p, zB, Alog, Dp, s0, yB);
  k_outproj<<<dim3(8, 17), 512, 0, stream>>>(yB, perm, ids, WoB, part2);
  k_ored2<<<NTOK * D_MODEL / 4 / 256, 256, 0, stream>>>(part2, out);
}